// Round 5
// baseline (12847.879 us; speedup 1.0000x reference)
//
#include <hip/hip_runtime.h>

typedef _Float16 f16;
typedef __attribute__((ext_vector_type(8))) _Float16 f16x8;
typedef __attribute__((ext_vector_type(4))) _Float16 f16x4;
typedef __attribute__((ext_vector_type(16))) float f32x16;

#define B_ 128
#define HID_ 1024
#define BH_ (B_ * HID_)   // 131072

// ------- cast + permute x: [B][T][D] f32 -> [T][B][D] f16 -------
__global__ __launch_bounds__(256) void k_cast_x(const float* __restrict__ x,
                                                f16* __restrict__ xf) {
    size_t g = (size_t)blockIdx.x * blockDim.x + threadIdx.x;
    size_t e = g * 4;
    const int d = (int)(e & 255);
    const int t = (int)((e >> 8) & 255);
    const int b = (int)(e >> 16);
    float4 v = ((const float4*)x)[g];
    f16x4 o = {(f16)v.x, (f16)v.y, (f16)v.z, (f16)v.w};
    *(f16x4*)(xf + ((size_t)t * B_ + b) * 256 + d) = o;
}

// ------- pack weights: src[K-span][4096] f32 -> per-WG swizzled f16 blocks -------
__global__ __launch_bounds__(256) void k_pack(const float* __restrict__ src,
                                              f16* __restrict__ dst,
                                              int Ktot, int koff) {
    __shared__ float tile[64][65];
    const int tx = threadIdx.x & 63, ty = threadIdx.x >> 6;
    const int r0 = blockIdx.y * 64, c0 = blockIdx.x * 64;
    #pragma unroll
    for (int r = ty; r < 64; r += 4)
        tile[r][tx] = src[(size_t)(r0 + r) * 4096 + c0 + tx];
    __syncthreads();
    const int k = koff + r0 + tx;
    #pragma unroll
    for (int rr = ty; rr < 64; rr += 4) {
        const int col = c0 + rr;
        const int g = col >> 10, hg = col & 1023;
        const int wg = hg >> 3, pcl = (g << 3) | (hg & 7);
        size_t off = ((size_t)wg * 32 + pcl) * Ktot + (((k >> 3) ^ (pcl & 7)) << 3) + (k & 7);
        dst[off] = (f16)tile[tx][rr];
    }
}

// ---------------- prep: biases, states, flags ----------------
__global__ __launch_bounds__(256) void k_prep(
    const float* __restrict__ bi1, const float* __restrict__ bh1,
    const float* __restrict__ bi2, const float* __restrict__ bh2,
    const float* __restrict__ h01, const float* __restrict__ h02,
    float* b1, float* b2, f16* h1r, f16* h2b,
    unsigned* flags1, unsigned* flags2) {
    int i = blockIdx.x * blockDim.x + threadIdx.x;
    if (i < 128) { flags1[i] = 0u; flags2[i] = 0u; }
    if (i < 4096) { b1[i] = bi1[i] + bh1[i]; b2[i] = bi2[i] + bh2[i]; }
    if (i < BH_) {
        h1r[i] = (f16)h01[i];   // h1 ring slot 0 = state before step 0
        h2b[i] = (f16)h02[i];   // h2 ring slot 0 = state before step 0
    }
}

__device__ __forceinline__ void publish4(f16* p, f16 a, f16 b) {
    union { struct { f16 x, y; } h; unsigned u; } cv;
    cv.h.x = a; cv.h.y = b;
    __hip_atomic_store((unsigned*)p, cv.u,
                       __ATOMIC_RELAXED, __HIP_MEMORY_SCOPE_AGENT);  // sc1 store
}

// wave-wide poll: spin until all 128 flags >= target (2 flags per lane)
__device__ __forceinline__ void poll_ge(const unsigned* flags, int target) {
    if (target <= 0) return;
    const int l2 = (threadIdx.x & 63) << 1;
    for (;;) {
        int f0 = (int)__hip_atomic_load(flags + l2,     __ATOMIC_RELAXED, __HIP_MEMORY_SCOPE_AGENT);
        int f1 = (int)__hip_atomic_load(flags + l2 + 1, __ATOMIC_RELAXED, __HIP_MEMORY_SCOPE_AGENT);
        if (__all(f0 >= target && f1 >= target)) break;
        __builtin_amdgcn_s_sleep(2);
    }
}

// ---------------- persistent, two decoupled barrier groups ----------------
// bids 0..127: layer1 (flags1, h1 4-slot ring). bids 128..255: layer2 (flags2).
__global__ __launch_bounds__(512, 1) void k_persist(
    const f16* __restrict__ Wp1, const f16* __restrict__ Wp2,
    const f16* __restrict__ xall,
    f16* h1r, f16* h2b, float* h2f,
    const float* __restrict__ b1, const float* __restrict__ b2,
    const float* __restrict__ c01, const float* __restrict__ c02,
    unsigned* flags1, unsigned* flags2) {
    __shared__ __align__(16) unsigned char smem[163840];
    f16*   Wl = (f16*)smem;                      // [32][K] 16B-chunk swizzled
    float* zl = (float*)(smem + 131072);         // 2 bufs x [128][32] swizzled

    const int bid = blockIdx.x;
    const int layer = bid >> 7;
    const int wg = bid & 127;
    const int tid = threadIdx.x;
    const int lane = tid & 63, wave = tid >> 6, hl = lane >> 5;
    const int pcl = lane & 31, swz = pcl & 7;
    const int K = layer ? 2048 : 1280;

    {   // weight slice -> LDS
        const f16* Wsrc = layer ? (Wp2 + (size_t)wg * 32 * 2048)
                                : (Wp1 + (size_t)wg * 32 * 1280);
        const int n = 32 * K / 8;
        for (int i = tid; i < n; i += 512)
            ((f16x8*)Wl)[i] = ((const f16x8*)Wsrc)[i];
    }

    const int m = tid & 127, q = tid >> 7;       // q: 0..3
    const int u0 = q * 2;
    const int ug0 = wg * 8 + u0;
    const float* csrc = layer ? c02 : c01;
    float c0 = csrc[(size_t)m * HID_ + ug0];
    float c1v = csrc[(size_t)m * HID_ + ug0 + 1];
    float biasr[4][2];
    {
        const float* bsrc = layer ? b2 : b1;
        #pragma unroll
        for (int g = 0; g < 4; ++g) {
            biasr[g][0] = bsrc[g * HID_ + ug0];
            biasr[g][1] = bsrc[g * HID_ + ug0 + 1];
        }
    }
    unsigned* myflags = layer ? flags2 : flags1;
    f16* hmine = layer ? h2b : h1r;

    f32x16 acc[4];
    #pragma unroll
    for (int mt = 0; mt < 4; ++mt)
        #pragma unroll
        for (int r = 0; r < 16; ++r) acc[mt][r] = 0.f;

    __syncthreads();

    for (int t = 0; t < 256; ++t) {
        if (layer == 0) {
            // ---- x-projection (immutable data; overlaps any waiting below) ----
            const f16* A0 = xall + (size_t)t * (B_ * 256);
            for (int c = wave; c < 16; c += 8) {
                const int ic = c * 2 + hl;
                f16x8 bfrag = *(const f16x8*)(Wl + pcl * 1280 + ((ic ^ swz) << 3));
                const f16* ap = A0 + (size_t)pcl * 256 + c * 16 + hl * 8;
                #pragma unroll
                for (int mt = 0; mt < 4; ++mt) {
                    f16x8 afrag = *(const f16x8*)(ap + (size_t)mt * 32 * 256);
                    acc[mt] = __builtin_amdgcn_mfma_f32_32x32x16_f16(afrag, bfrag, acc[mt], 0, 0, 0);
                }
            }
            // ---- wait: own group step t-1 done; ring guard vs layer2 ----
            if (wave == 0) {
                poll_ge(flags1, t);
                __builtin_amdgcn_fence(__ATOMIC_ACQUIRE, "agent");   // buffer_inv
            } else if (wave == 1) {
                poll_ge(flags2, t - 3);                              // write-after-read guard
            }
            __syncthreads();
            // ---- recurrent part: h1_state[t-1] at slot t&3 ----
            const f16* A1 = h1r + (size_t)(t & 3) * BH_;
            for (int c = 16 + wave; c < 80; c += 8) {
                const int ic = c * 2 + hl;
                f16x8 bfrag = *(const f16x8*)(Wl + pcl * 1280 + ((ic ^ swz) << 3));
                const f16* ap = A1 + (size_t)pcl * HID_ + (c * 16 - 256) + hl * 8;
                #pragma unroll
                for (int mt = 0; mt < 4; ++mt) {
                    f16x8 afrag = *(const f16x8*)(ap + (size_t)mt * 32 * HID_);
                    acc[mt] = __builtin_amdgcn_mfma_f32_32x32x16_f16(afrag, bfrag, acc[mt], 0, 0, 0);
                }
            }
        } else {
            // ---- phase A: wait for h1_state[t], then A0 GEMM (off critical path) ----
            if (wave == 0) {
                poll_ge(flags1, t + 1);
                __builtin_amdgcn_fence(__ATOMIC_ACQUIRE, "agent");
            }
            __syncthreads();
            const f16* A0 = h1r + (size_t)((t + 1) & 3) * BH_;
            for (int c = wave; c < 64; c += 8) {
                const int ic = c * 2 + hl;
                f16x8 bfrag = *(const f16x8*)(Wl + pcl * 2048 + ((ic ^ swz) << 3));
                const f16* ap = A0 + (size_t)pcl * HID_ + c * 16 + hl * 8;
                #pragma unroll
                for (int mt = 0; mt < 4; ++mt) {
                    f16x8 afrag = *(const f16x8*)(ap + (size_t)mt * 32 * HID_);
                    acc[mt] = __builtin_amdgcn_mfma_f32_32x32x16_f16(afrag, bfrag, acc[mt], 0, 0, 0);
                }
            }
            // ---- phase B: wait own group step t-1, then A1 GEMM (critical path) ----
            if (wave == 0) {
                poll_ge(flags2, t);
                __builtin_amdgcn_fence(__ATOMIC_ACQUIRE, "agent");
            }
            __syncthreads();
            const f16* A1 = h2b + (size_t)(t & 1) * BH_;
            for (int c = 64 + wave; c < 128; c += 8) {
                const int ic = c * 2 + hl;
                f16x8 bfrag = *(const f16x8*)(Wl + pcl * 2048 + ((ic ^ swz) << 3));
                const f16* ap = A1 + (size_t)pcl * HID_ + (c * 16 - 1024) + hl * 8;
                #pragma unroll
                for (int mt = 0; mt < 4; ++mt) {
                    f16x8 afrag = *(const f16x8*)(ap + (size_t)mt * 32 * HID_);
                    acc[mt] = __builtin_amdgcn_mfma_f32_32x32x16_f16(afrag, bfrag, acc[mt], 0, 0, 0);
                }
            }
        }

        // ---- z-reduction: waves 0,1 write bufs; waves 2..7 ds_add ----
        float* Z = zl + (size_t)(wave & 1) * 4096;
        if (wave < 2) {
            #pragma unroll
            for (int mt = 0; mt < 4; ++mt)
                #pragma unroll
                for (int r = 0; r < 16; ++r) {
                    const int row = mt * 32 + (r & 3) + 8 * (r >> 2) + 4 * hl;
                    Z[row * 32 + (pcl ^ (row & 31))] = acc[mt][r];
                }
        }
        __syncthreads();
        if (wave >= 2) {
            #pragma unroll
            for (int mt = 0; mt < 4; ++mt)
                #pragma unroll
                for (int r = 0; r < 16; ++r) {
                    const int row = mt * 32 + (r & 3) + 8 * (r >> 2) + 4 * hl;
                    atomicAdd(&Z[row * 32 + (pcl ^ (row & 31))], acc[mt][r]);
                }
        }
        __syncthreads();
        #pragma unroll
        for (int mt = 0; mt < 4; ++mt)
            #pragma unroll
            for (int r = 0; r < 16; ++r) acc[mt][r] = 0.f;

        // ---- elementwise: 2 cells per thread ----
        float zg[4][2];
        #pragma unroll
        for (int g = 0; g < 4; ++g)
            #pragma unroll
            for (int j = 0; j < 2; ++j) {
                const int cc = g * 8 + u0 + j;
                const int idx = m * 32 + (cc ^ (m & 31));
                zg[g][j] = zl[idx] + zl[4096 + idx] + biasr[g][j];
            }
        f16 ho[2];
        float hf[2];
        #pragma unroll
        for (int j = 0; j < 2; ++j) {
            const float fg = 1.f / (1.f + __expf(-zg[0][j]));
            const float ig = 1.f / (1.f + __expf(-zg[1][j]));
            const float gg = 1.f - 2.f / (__expf(2.f * zg[2][j]) + 1.f);
            const float og = 1.f / (1.f + __expf(-zg[3][j]));
            const float cv = j ? c1v : c0;
            const float cn = cv * fg + ig * gg;
            if (j) c1v = cn; else c0 = cn;
            const float h = (1.f - 2.f / (__expf(2.f * cn) + 1.f)) * og;
            ho[j] = (f16)h;
            hf[j] = h;
        }
        const int wslot = layer ? ((t + 1) & 1) : ((t + 1) & 3);
        publish4(hmine + (size_t)wslot * BH_ + (size_t)m * HID_ + ug0, ho[0], ho[1]);
        if (layer == 1 && t == 255) {
            h2f[(size_t)m * HID_ + ug0]     = hf[0];
            h2f[(size_t)m * HID_ + ug0 + 1] = hf[1];
        }

        // ---- release: own stores at coherence point, then flag ----
        asm volatile("s_waitcnt vmcnt(0)" ::: "memory");
        __syncthreads();
        if (tid == 0)
            __hip_atomic_store(myflags + wg, (unsigned)(t + 1),
                               __ATOMIC_RELAXED, __HIP_MEMORY_SCOPE_AGENT);
    }
}

// ---------------- final: y = h2 @ Wc + bc (fp32) ----------------
__global__ __launch_bounds__(64) void k_final(const float* __restrict__ h2f,
                                              const float* __restrict__ Wc,
                                              const float* __restrict__ bc,
                                              float* __restrict__ y) {
    const int b = blockIdx.x, lane = threadIdx.x;
    float acc[10] = {0, 0, 0, 0, 0, 0, 0, 0, 0, 0};
    for (int k = lane; k < HID_; k += 64) {
        const float h = h2f[b * HID_ + k];
        #pragma unroll
        for (int j = 0; j < 10; ++j) acc[j] = fmaf(h, Wc[k * 10 + j], acc[j]);
    }
    #pragma unroll
    for (int off = 32; off; off >>= 1)
        #pragma unroll
        for (int j = 0; j < 10; ++j) acc[j] += __shfl_down(acc[j], off);
    if (lane == 0) {
        #pragma unroll
        for (int j = 0; j < 10; ++j) y[b * 10 + j] = acc[j] + bc[j];
    }
}

extern "C" void kernel_launch(void* const* d_in, const int* in_sizes, int n_in,
                              void* d_out, int out_size, void* d_ws, size_t ws_size,
                              hipStream_t stream) {
    (void)in_sizes; (void)n_in; (void)out_size; (void)ws_size;
    const float* x   = (const float*)d_in[0];
    const float* h01 = (const float*)d_in[1];
    const float* c01 = (const float*)d_in[2];
    const float* h02 = (const float*)d_in[3];
    const float* c02 = (const float*)d_in[4];
    const float* Wi1 = (const float*)d_in[5];
    const float* Wh1 = (const float*)d_in[6];
    const float* bi1 = (const float*)d_in[7];
    const float* bh1 = (const float*)d_in[8];
    const float* Wi2 = (const float*)d_in[9];
    const float* Wh2 = (const float*)d_in[10];
    const float* bi2 = (const float*)d_in[11];
    const float* bh2 = (const float*)d_in[12];
    const float* Wc  = (const float*)d_in[13];
    const float* bc  = (const float*)d_in[14];
    float* y = (float*)d_out;

    char* w = (char*)d_ws;
    f16*   xall = (f16*)(w + 0);            // 16,777,216
    f16*   Wp1  = (f16*)(w + 16777216);     // 10,485,760
    f16*   Wp2  = (f16*)(w + 27262976);     // 16,777,216
    f16*   h1r  = (f16*)(w + 44040192);     // [4][128][1024] f16 = 1,048,576
    f16*   h2b  = (f16*)(w + 45088768);     // [2][128][1024] f16 =   524,288
    float* h2f  = (float*)(w + 45613056);   //    524,288
    float* b1   = (float*)(w + 46137344);   //     16,384
    float* b2   = (float*)(w + 46153728);   //     16,384
    unsigned* flags1 = (unsigned*)(w + 46170112);  // 512
    unsigned* flags2 = (unsigned*)(w + 46170624);  // 512

    k_cast_x<<<8192, 256, 0, stream>>>(x, xall);
    k_pack<<<dim3(64, 4),  256, 0, stream>>>(Wi1, Wp1, 1280, 0);
    k_pack<<<dim3(64, 16), 256, 0, stream>>>(Wh1, Wp1, 1280, 256);
    k_pack<<<dim3(64, 16), 256, 0, stream>>>(Wi2, Wp2, 2048, 0);
    k_pack<<<dim3(64, 16), 256, 0, stream>>>(Wh2, Wp2, 2048, 1024);
    k_prep<<<512, 256, 0, stream>>>(bi1, bh1, bi2, bh2, h01, h02,
                                    b1, b2, h1r, h2b, flags1, flags2);

    k_persist<<<256, 512, 0, stream>>>(Wp1, Wp2, xall, h1r, h2b, h2f,
                                       b1, b2, c01, c02, flags1, flags2);

    k_final<<<128, 64, 0, stream>>>(h2f, Wc, bc, y);
}

// Round 6
// 10886.635 us; speedup vs baseline: 1.1802x; 1.1802x over previous
//
#include <hip/hip_runtime.h>

typedef _Float16 f16;
typedef __attribute__((ext_vector_type(8))) _Float16 f16x8;
typedef __attribute__((ext_vector_type(4))) _Float16 f16x4;
typedef __attribute__((ext_vector_type(16))) float f32x16;

#define B_ 128
#define HID_ 1024
#define BH_ (B_ * HID_)   // 131072 elements per ring slot

// sc0+sc1 load: bypass L1+L2, serviced at the coherence point (L3). vmcnt-tracked by hand.
#define LD16(dst, p) asm volatile("global_load_dwordx4 %0, %1, off sc0 sc1" : "=v"(dst) : "v"(p))
#define LD4X(buf, p) do { LD16(buf[0], (p)); LD16(buf[1], (p) + 256); \
                          LD16(buf[2], (p) + 512); LD16(buf[3], (p) + 768); } while (0)
#define WAITVM(N) do { asm volatile("s_waitcnt vmcnt(" #N ")" ::: "memory"); \
                       __builtin_amdgcn_sched_barrier(0); } while (0)

// ------- cast + permute x: [B][T][D] f32 -> [T][D/8][B][8] f16 (blocked) -------
__global__ __launch_bounds__(256) void k_cast_x(const float* __restrict__ x,
                                                f16* __restrict__ xf) {
    size_t g = (size_t)blockIdx.x * blockDim.x + threadIdx.x;
    size_t e = g * 4;
    const int d = (int)(e & 255);
    const int t = (int)((e >> 8) & 255);
    const int b = (int)(e >> 16);
    float4 v = ((const float4*)x)[g];
    f16x4 o = {(f16)v.x, (f16)v.y, (f16)v.z, (f16)v.w};
    *(f16x4*)(xf + (((size_t)t * 32 + (d >> 3)) * 128 + b) * 8 + (d & 7)) = o;
}

// ------- pack weights: src[K-span][4096] f32 -> per-WG swizzled f16 blocks -------
__global__ __launch_bounds__(256) void k_pack(const float* __restrict__ src,
                                              f16* __restrict__ dst,
                                              int Ktot, int koff) {
    __shared__ float tile[64][65];
    const int tx = threadIdx.x & 63, ty = threadIdx.x >> 6;
    const int r0 = blockIdx.y * 64, c0 = blockIdx.x * 64;
    #pragma unroll
    for (int r = ty; r < 64; r += 4)
        tile[r][tx] = src[(size_t)(r0 + r) * 4096 + c0 + tx];
    __syncthreads();
    const int k = koff + r0 + tx;
    #pragma unroll
    for (int rr = ty; rr < 64; rr += 4) {
        const int col = c0 + rr;
        const int g = col >> 10, hg = col & 1023;
        const int wg = hg >> 3, pcl = (g << 3) | (hg & 7);
        size_t off = ((size_t)wg * 32 + pcl) * Ktot + (((k >> 3) ^ (pcl & 7)) << 3) + (k & 7);
        dst[off] = (f16)tile[tx][rr];
    }
}

// ---------------- prep: biases, states (blocked layout), flags ----------------
__global__ __launch_bounds__(256) void k_prep(
    const float* __restrict__ bi1, const float* __restrict__ bh1,
    const float* __restrict__ bi2, const float* __restrict__ bh2,
    const float* __restrict__ h01, const float* __restrict__ h02,
    float* b1, float* b2, f16* h1r, f16* h2b, unsigned* flags) {
    int i = blockIdx.x * blockDim.x + threadIdx.x;
    if (i < 256) flags[i] = 0u;
    if (i < 4096) { b1[i] = bi1[i] + bh1[i]; b2[i] = bi2[i] + bh2[i]; }
    if (i < BH_) {
        const int b = i >> 10, u = i & 1023;
        const size_t off = (((size_t)(u >> 3)) * 128 + b) * 8 + (u & 7);
        h1r[off] = (f16)h01[i];   // slot 0 = h1 state before step 0
        h2b[off] = (f16)h02[i];   // slot 0 = h2 state before step 0
    }
}

__device__ __forceinline__ void publish4(f16* p, f16 a, f16 b) {
    union { struct { f16 x, y; } h; unsigned u; } cv;
    cv.h.x = a; cv.h.y = b;
    __hip_atomic_store((unsigned*)p, cv.u,
                       __ATOMIC_RELAXED, __HIP_MEMORY_SCOPE_AGENT);
}

// wave-wide poll: all 256 flags >= target (4 flags per lane, contiguous)
__device__ __forceinline__ void poll_all(const unsigned* flags, unsigned target) {
    const int l4 = (threadIdx.x & 63) << 2;
    for (;;) {
        unsigned f0 = __hip_atomic_load(flags + l4 + 0, __ATOMIC_RELAXED, __HIP_MEMORY_SCOPE_AGENT);
        unsigned f1 = __hip_atomic_load(flags + l4 + 1, __ATOMIC_RELAXED, __HIP_MEMORY_SCOPE_AGENT);
        unsigned f2 = __hip_atomic_load(flags + l4 + 2, __ATOMIC_RELAXED, __HIP_MEMORY_SCOPE_AGENT);
        unsigned f3 = __hip_atomic_load(flags + l4 + 3, __ATOMIC_RELAXED, __HIP_MEMORY_SCOPE_AGENT);
        if (__all(f0 >= target && f1 >= target && f2 >= target && f3 >= target)) break;
        __builtin_amdgcn_s_sleep(2);
    }
}

// depth-2 software-pipelined GEMM over one K=1024 operand read with sc1 loads.
// A layout: [128 groups][128 rows][8]; wave handles chunks c = wave + 8*i, i=0..7.
template<int KW, int KOFFC>
__device__ __forceinline__ void gemm_h(const f16* __restrict__ Ab, const f16* Wl,
                                       const int wave, const int hl, const int pcl,
                                       const int swz, f32x16 (&acc)[4]) {
    f16x8 u0[4], u1[4], u2[4];
    const f16* pb = Ab + ((size_t)(wave * 2 + hl) * 128 + pcl) * 8;
    WAITVM(0);                                  // clean vmcnt slate
    LD4X(u0, pb);                               // iter 0
    LD4X(u1, pb + 16384);                       // iter 1
    #pragma unroll
    for (int i = 0; i < 8; ++i) {
        const int ic = (KOFFC + wave + 8 * i) * 2 + hl;
        f16x8 bf = *(const f16x8*)(Wl + pcl * KW + ((ic ^ swz) << 3));
        if (i < 6) {
            const f16* pn = pb + (size_t)(i + 2) * 16384;
            if ((i % 3) == 0)      LD4X(u2, pn);
            else if ((i % 3) == 1) LD4X(u0, pn);
            else                   LD4X(u1, pn);
            WAITVM(8);
        } else if (i == 6) {
            WAITVM(4);
        } else {
            WAITVM(0);
        }
        #define MFMA4(BUF) do { \
            acc[0] = __builtin_amdgcn_mfma_f32_32x32x16_f16(BUF[0], bf, acc[0], 0, 0, 0); \
            acc[1] = __builtin_amdgcn_mfma_f32_32x32x16_f16(BUF[1], bf, acc[1], 0, 0, 0); \
            acc[2] = __builtin_amdgcn_mfma_f32_32x32x16_f16(BUF[2], bf, acc[2], 0, 0, 0); \
            acc[3] = __builtin_amdgcn_mfma_f32_32x32x16_f16(BUF[3], bf, acc[3], 0, 0, 0); } while (0)
        if ((i % 3) == 0)      MFMA4(u0);
        else if ((i % 3) == 1) MFMA4(u1);
        else                   MFMA4(u2);
        #undef MFMA4
    }
}

// ---------------- persistent: single barrier group, no cache invalidates ----------------
__global__ __launch_bounds__(512, 1) void k_persist(
    const f16* __restrict__ Wp1, const f16* __restrict__ Wp2,
    const f16* __restrict__ xall,              // [256][32][128][8]
    f16* h1r, f16* h2b,                        // [2][128][128][8] rings
    float* h2f,                                // [128][1024] final h2
    const float* __restrict__ b1, const float* __restrict__ b2,
    const float* __restrict__ c01, const float* __restrict__ c02,
    unsigned* flags) {
    __shared__ __align__(16) unsigned char smem[163840];
    f16*   Wl = (f16*)smem;                    // [32][K] 16B-chunk swizzled
    float* zl = (float*)(smem + 131072);       // 2 bufs x [128][32] swizzled

    const int bid = blockIdx.x;
    const int layer = bid >> 7;
    const int wg = bid & 127;
    const int tid = threadIdx.x;
    const int lane = tid & 63, wave = tid >> 6, hl = lane >> 5;
    const int pcl = lane & 31, swz = pcl & 7;
    const int K = layer ? 2048 : 1280;

    {   // weight slice -> LDS
        const f16* Wsrc = layer ? (Wp2 + (size_t)wg * 32 * 2048)
                                : (Wp1 + (size_t)wg * 32 * 1280);
        const int n = 32 * K / 8;
        for (int i = tid; i < n; i += 512)
            ((f16x8*)Wl)[i] = ((const f16x8*)Wsrc)[i];
    }

    const int m = tid & 127, q = tid >> 7;
    const int ug0 = wg * 8 + q * 2;
    const float* csrc = layer ? c02 : c01;
    float c0 = csrc[(size_t)m * HID_ + ug0];
    float c1v = csrc[(size_t)m * HID_ + ug0 + 1];
    float biasr[4][2];
    {
        const float* bsrc = layer ? b2 : b1;
        #pragma unroll
        for (int g = 0; g < 4; ++g) {
            biasr[g][0] = bsrc[g * HID_ + ug0];
            biasr[g][1] = bsrc[g * HID_ + ug0 + 1];
        }
    }
    f16* hmine = layer ? h2b : h1r;

    f32x16 acc[4];
    #pragma unroll
    for (int mt = 0; mt < 4; ++mt)
        #pragma unroll
        for (int r = 0; r < 16; ++r) acc[mt][r] = 0.f;

    __syncthreads();

    for (int s = 0; s <= 256; ++s) {
        // ---- barrier: everyone finished stage s-1 (flag == s) ----
        if (s > 0) {
            if (wave == 0) poll_all(flags, (unsigned)s);
            __syncthreads();
        }

        const bool active = layer == 0 ? (s < 256) : (s >= 1);
        if (active) {
            if (layer == 0) {
                // x-projection: 16 chunks, normal cached loads (x immutable)
                const f16* xt = xall + (size_t)s * 32768;
                #pragma unroll
                for (int j = 0; j < 2; ++j) {
                    const int c = wave * 2 + j;
                    const int ic = c * 2 + hl;
                    f16x8 bf = *(const f16x8*)(Wl + pcl * 1280 + ((ic ^ swz) << 3));
                    const f16* ap = xt + ((size_t)(c * 2 + hl) * 128 + pcl) * 8;
                    acc[0] = __builtin_amdgcn_mfma_f32_32x32x16_f16(*(const f16x8*)(ap), bf, acc[0], 0, 0, 0);
                    acc[1] = __builtin_amdgcn_mfma_f32_32x32x16_f16(*(const f16x8*)(ap + 256), bf, acc[1], 0, 0, 0);
                    acc[2] = __builtin_amdgcn_mfma_f32_32x32x16_f16(*(const f16x8*)(ap + 512), bf, acc[2], 0, 0, 0);
                    acc[3] = __builtin_amdgcn_mfma_f32_32x32x16_f16(*(const f16x8*)(ap + 768), bf, acc[3], 0, 0, 0);
                }
                // recurrent part: h1 state[s-1] at slot s&1, sc1-pipelined
                gemm_h<1280, 16>(h1r + (size_t)(s & 1) * BH_, Wl, wave, hl, pcl, swz, acc);
            } else {
                gemm_h<2048, 0>(h1r + (size_t)(s & 1) * BH_, Wl, wave, hl, pcl, swz, acc);
                gemm_h<2048, 64>(h2b + (size_t)((s - 1) & 1) * BH_, Wl, wave, hl, pcl, swz, acc);
            }

            // ---- z-reduction: waves 0,1 write bufs; waves 2..7 LDS atomic add ----
            float* Z = zl + (size_t)(wave & 1) * 4096;
            if (wave < 2) {
                #pragma unroll
                for (int mt = 0; mt < 4; ++mt)
                    #pragma unroll
                    for (int r = 0; r < 16; ++r) {
                        const int row = mt * 32 + (r & 3) + 8 * (r >> 2) + 4 * hl;
                        Z[row * 32 + (pcl ^ (row & 31))] = acc[mt][r];
                    }
            }
            __syncthreads();
            if (wave >= 2) {
                #pragma unroll
                for (int mt = 0; mt < 4; ++mt)
                    #pragma unroll
                    for (int r = 0; r < 16; ++r) {
                        const int row = mt * 32 + (r & 3) + 8 * (r >> 2) + 4 * hl;
                        atomicAdd(&Z[row * 32 + (pcl ^ (row & 31))], acc[mt][r]);
                    }
            }
            __syncthreads();
            #pragma unroll
            for (int mt = 0; mt < 4; ++mt)
                #pragma unroll
                for (int r = 0; r < 16; ++r) acc[mt][r] = 0.f;

            // ---- elementwise: 2 cells per thread ----
            float zg[4][2];
            #pragma unroll
            for (int g = 0; g < 4; ++g)
                #pragma unroll
                for (int j = 0; j < 2; ++j) {
                    const int cc = g * 8 + q * 2 + j;
                    const int idx = m * 32 + (cc ^ (m & 31));
                    zg[g][j] = zl[idx] + zl[4096 + idx] + biasr[g][j];
                }
            f16 ho[2];
            float hfv[2];
            #pragma unroll
            for (int j = 0; j < 2; ++j) {
                const float fg = 1.f / (1.f + __expf(-zg[0][j]));
                const float ig = 1.f / (1.f + __expf(-zg[1][j]));
                const float gg = 1.f - 2.f / (__expf(2.f * zg[2][j]) + 1.f);
                const float og = 1.f / (1.f + __expf(-zg[3][j]));
                const float cv = j ? c1v : c0;
                const float cn = cv * fg + ig * gg;
                if (j) c1v = cn; else c0 = cn;
                const float h = (1.f - 2.f / (__expf(2.f * cn) + 1.f)) * og;
                ho[j] = (f16)h;
                hfv[j] = h;
            }
            const int u = layer ? s : (s + 1);               // step index + 1 written
            const int wslot = u & 1;
            publish4(hmine + (size_t)wslot * BH_ + ((size_t)wg * 128 + m) * 8 + q * 2,
                     ho[0], ho[1]);
            if (layer == 1 && s == 256) {
                h2f[(size_t)m * HID_ + ug0]     = hfv[0];
                h2f[(size_t)m * HID_ + ug0 + 1] = hfv[1];
            }
        }

        // ---- release: drain sc1 stores, then per-WG flag ----
        if (s < 256) {
            asm volatile("s_waitcnt vmcnt(0)" ::: "memory");
            __syncthreads();
            if (tid == 0)
                __hip_atomic_store(flags + bid, (unsigned)(s + 1),
                                   __ATOMIC_RELAXED, __HIP_MEMORY_SCOPE_AGENT);
        }
    }
}

// ---------------- final: y = h2 @ Wc + bc (fp32) ----------------
__global__ __launch_bounds__(64) void k_final(const float* __restrict__ h2f,
                                              const float* __restrict__ Wc,
                                              const float* __restrict__ bc,
                                              float* __restrict__ y) {
    const int b = blockIdx.x, lane = threadIdx.x;
    float acc[10] = {0, 0, 0, 0, 0, 0, 0, 0, 0, 0};
    for (int k = lane; k < HID_; k += 64) {
        const float h = h2f[b * HID_ + k];
        #pragma unroll
        for (int j = 0; j < 10; ++j) acc[j] = fmaf(h, Wc[k * 10 + j], acc[j]);
    }
    #pragma unroll
    for (int off = 32; off; off >>= 1)
        #pragma unroll
        for (int j = 0; j < 10; ++j) acc[j] += __shfl_down(acc[j], off);
    if (lane == 0) {
        #pragma unroll
        for (int j = 0; j < 10; ++j) y[b * 10 + j] = acc[j] + bc[j];
    }
}

extern "C" void kernel_launch(void* const* d_in, const int* in_sizes, int n_in,
                              void* d_out, int out_size, void* d_ws, size_t ws_size,
                              hipStream_t stream) {
    (void)in_sizes; (void)n_in; (void)out_size; (void)ws_size;
    const float* x   = (const float*)d_in[0];
    const float* h01 = (const float*)d_in[1];
    const float* c01 = (const float*)d_in[2];
    const float* h02 = (const float*)d_in[3];
    const float* c02 = (const float*)d_in[4];
    const float* Wi1 = (const float*)d_in[5];
    const float* Wh1 = (const float*)d_in[6];
    const float* bi1 = (const float*)d_in[7];
    const float* bh1 = (const float*)d_in[8];
    const float* Wi2 = (const float*)d_in[9];
    const float* Wh2 = (const float*)d_in[10];
    const float* bi2 = (const float*)d_in[11];
    const float* bh2 = (const float*)d_in[12];
    const float* Wc  = (const float*)d_in[13];
    const float* bc  = (const float*)d_in[14];
    float* y = (float*)d_out;

    char* w = (char*)d_ws;
    f16*   xall = (f16*)(w + 0);            // 16,777,216
    f16*   Wp1  = (f16*)(w + 16777216);     // 10,485,760
    f16*   Wp2  = (f16*)(w + 27262976);     // 16,777,216
    f16*   h1r  = (f16*)(w + 44040192);     // [2] slots =   524,288
    f16*   h2b  = (f16*)(w + 44564480);     // [2] slots =   524,288
    float* h2f  = (float*)(w + 45088768);   //    524,288
    float* b1   = (float*)(w + 45613056);   //     16,384
    float* b2   = (float*)(w + 45629440);   //     16,384
    unsigned* flags = (unsigned*)(w + 45645824);   // 1,024

    k_cast_x<<<8192, 256, 0, stream>>>(x, xall);
    k_pack<<<dim3(64, 4),  256, 0, stream>>>(Wi1, Wp1, 1280, 0);
    k_pack<<<dim3(64, 16), 256, 0, stream>>>(Wh1, Wp1, 1280, 256);
    k_pack<<<dim3(64, 16), 256, 0, stream>>>(Wi2, Wp2, 2048, 0);
    k_pack<<<dim3(64, 16), 256, 0, stream>>>(Wh2, Wp2, 2048, 1024);
    k_prep<<<512, 256, 0, stream>>>(bi1, bh1, bi2, bh2, h01, h02,
                                    b1, b2, h1r, h2b, flags);

    k_persist<<<256, 512, 0, stream>>>(Wp1, Wp2, xall, h1r, h2b, h2f,
                                       b1, b2, c01, c02, flags);

    k_final<<<128, 64, 0, stream>>>(h2f, Wc, bc, y);
}